// Round 6
// baseline (105.149 us; speedup 1.0000x reference)
//
#include <hip/hip_runtime.h>
#include <hip/hip_bf16.h>

// Problem constants (fixed by reference): B=4, C=64, H=W=64, N=4096
#define BATCH 4
#define NSP   4096

typedef __bf16 bf16x8v __attribute__((ext_vector_type(8)));
typedef __bf16 bf16x4v __attribute__((ext_vector_type(4)));
typedef float  floatx4 __attribute__((ext_vector_type(4)));
typedef short  shortx4 __attribute__((ext_vector_type(4)));

// K=16 bf16 MFMA for direct D->B operand feeding (PV without LDS roundtrip).
#if __has_builtin(__builtin_amdgcn_mfma_f32_16x16x16bf16_1k)
#define HAVE_MFMA16 1
static __device__ inline floatx4 mfma16(bf16x4v a, bf16x4v b, floatx4 c) {
    return __builtin_amdgcn_mfma_f32_16x16x16bf16_1k(
        __builtin_bit_cast(shortx4, a), __builtin_bit_cast(shortx4, b), c, 0, 0, 0);
}
#elif __has_builtin(__builtin_amdgcn_mfma_f32_16x16x16_bf16)
#define HAVE_MFMA16 1
static __device__ inline floatx4 mfma16(bf16x4v a, bf16x4v b, floatx4 c) {
    return __builtin_amdgcn_mfma_f32_16x16x16_bf16(a, b, c, 0, 0, 0);
}
#else
#define HAVE_MFMA16 0
#endif

// ---------------------------------------------------------------------------
// Kernel 1: qkT[b][n][o] = bf16( (sum_c W[o][c]*x[b][c][n] + bias[o]) / 64 )
// 1/64 pre-scale on both Q and K makes attn scores come out scaled by 1/4096.
// ---------------------------------------------------------------------------
__global__ __launch_bounds__(256) void qk_kernel(const float* __restrict__ x,
                                                 const float* __restrict__ Wm,
                                                 const float* __restrict__ bias,
                                                 __bf16* __restrict__ qkT) {
    __shared__ __align__(16) __bf16 xT[64 * 72];   // [n][c]; reused as [n][o] out buf

    const int t  = threadIdx.x;
    const int b  = blockIdx.x >> 6;
    const int n0 = (blockIdx.x & 63) << 6;

#pragma unroll
    for (int p = 0; p < 4; ++p) {
        const int c  = p * 16 + (t >> 4);
        const int n4 = (t & 15) * 4;
        const float4 v = *(const float4*)(x + (size_t)(b * 64 + c) * 4096 + n0 + n4);
        xT[(n4 + 0) * 72 + c] = (__bf16)(v.x * 0.015625f);
        xT[(n4 + 1) * 72 + c] = (__bf16)(v.y * 0.015625f);
        xT[(n4 + 2) * 72 + c] = (__bf16)(v.z * 0.015625f);
        xT[(n4 + 3) * 72 + c] = (__bf16)(v.w * 0.015625f);
    }
    __syncthreads();

    const int w = t >> 6, lane = t & 63, quad = lane >> 4, l16 = lane & 15;
    const bf16x8v a0 = *(const bf16x8v*)(xT + (w * 16 + l16) * 72 + quad * 8);
    const bf16x8v a1 = *(const bf16x8v*)(xT + (w * 16 + l16) * 72 + 32 + quad * 8);

    floatx4 acc[4];
#pragma unroll
    for (int ot = 0; ot < 4; ++ot) {
        const float* wr = Wm + (ot * 16 + l16) * 64;
        float4 wa = *(const float4*)(wr + quad * 8);
        float4 wb = *(const float4*)(wr + quad * 8 + 4);
        float4 wc = *(const float4*)(wr + 32 + quad * 8);
        float4 wd = *(const float4*)(wr + 32 + quad * 8 + 4);
        bf16x8v b0, b1;
        b0[0]=(__bf16)wa.x; b0[1]=(__bf16)wa.y; b0[2]=(__bf16)wa.z; b0[3]=(__bf16)wa.w;
        b0[4]=(__bf16)wb.x; b0[5]=(__bf16)wb.y; b0[6]=(__bf16)wb.z; b0[7]=(__bf16)wb.w;
        b1[0]=(__bf16)wc.x; b1[1]=(__bf16)wc.y; b1[2]=(__bf16)wc.z; b1[3]=(__bf16)wc.w;
        b1[4]=(__bf16)wd.x; b1[5]=(__bf16)wd.y; b1[6]=(__bf16)wd.z; b1[7]=(__bf16)wd.w;
        acc[ot] = floatx4{0.f, 0.f, 0.f, 0.f};
        acc[ot] = __builtin_amdgcn_mfma_f32_16x16x32_bf16(a0, b0, acc[ot], 0, 0, 0);
        acc[ot] = __builtin_amdgcn_mfma_f32_16x16x32_bf16(a1, b1, acc[ot], 0, 0, 0);
    }
    __syncthreads();

#pragma unroll
    for (int ot = 0; ot < 4; ++ot) {
        const float bo = bias[ot * 16 + l16] * 0.015625f;
#pragma unroll
        for (int r = 0; r < 4; ++r)
            xT[(w * 16 + quad * 4 + r) * 72 + ot * 16 + l16] = (__bf16)(acc[ot][r] + bo);
    }
    __syncthreads();

    const int n = t >> 2, seg = t & 3;
    __bf16* dst = qkT + (size_t)(b * 4096 + n0 + n) * 64 + seg * 16;
    *(bf16x8v*)dst       = *(const bf16x8v*)(xT + n * 72 + seg * 16);
    *(bf16x8v*)(dst + 8) = *(const bf16x8v*)(xT + n * 72 + seg * 16 + 8);
}

// ---------------------------------------------------------------------------
// Kernel 2: flash-style attention. Block = (b, 128-q tile, m-chunk). 4 waves
// x 32 q. S^T = K·Q^T; exp results feed PV directly as K=16 MFMA B-operands
// (no LDS roundtrip) when HAVE_MFMA16. Register-prefetched staging.
// ---------------------------------------------------------------------------
template<int SPLIT, int ITERS>
__global__ __launch_bounds__(256, 4) void attn_kernel(const float* __restrict__ x,
                                                      const __bf16* __restrict__ qkT,
                                                      __bf16* __restrict__ Opart,
                                                      float* __restrict__ Lpart) {
    __shared__ __align__(16) char smem[36864];
    __bf16* Klds = (__bf16*)smem;                 // [64 m][72 c]
    __bf16* Vlds = (__bf16*)(smem + 9216);        // [64 c][72 m]
#if !HAVE_MFMA16
    __bf16* Plds = (__bf16*)(smem + 18432);       // [128 q][72 m]
#endif
    float*  Olds = (float*)smem;                  // epilogue alias: [64 c][132 q]

    const int t   = threadIdx.x;
    const int blk = blockIdx.x;
    const int xcd = blk & 7;                      // XCD round-robin
    const int b   = xcd >> 1;                     // each b pinned to 2 XCDs
    const int sub = ((blk >> 3) << 1) | (xcd & 1);
    const int qt  = sub / SPLIT;
    const int s   = sub % SPLIT;
    const int n0  = qt << 7;
    const int pblk = (b * 32 + qt) * SPLIT + s;

    const int w = t >> 6, lane = t & 63, quad = lane >> 4, l16 = lane & 15;

    // Q B-frags: B[k=c][n=q], q = w*32 + qt2*16 + l16
    bf16x8v fq[2][2];
#pragma unroll
    for (int qt2 = 0; qt2 < 2; ++qt2) {
        const __bf16* qrow = qkT + (size_t)(b * 4096 + n0 + w * 32 + qt2 * 16 + l16) * 64;
        fq[qt2][0] = *(const bf16x8v*)(qrow + quad * 8);
        fq[qt2][1] = *(const bf16x8v*)(qrow + 32 + quad * 8);
    }

    floatx4 oacc[2][4];
#pragma unroll
    for (int i = 0; i < 2; ++i)
#pragma unroll
        for (int j = 0; j < 4; ++j) oacc[i][j] = floatx4{0.f, 0.f, 0.f, 0.f};
    float rs[2] = {0.f, 0.f};

    // register prefetch buffers for next tile
    uint4  kpre[2];
    float4 vpre[4];
    {
        const int m0 = s * (64 * ITERS);
#pragma unroll
        for (int i = 0; i < 2; ++i) {
            int idx = t + 256 * i;
            kpre[i] = *(const uint4*)(qkT + (size_t)(b * 4096 + m0 + (idx >> 3)) * 64 + (idx & 7) * 8);
        }
#pragma unroll
        for (int i = 0; i < 4; ++i) {
            int idx = t + 256 * i;
            vpre[i] = *(const float4*)(x + (size_t)(b * 64 + (idx >> 4)) * 4096 + m0 + (idx & 15) * 4);
        }
    }

    for (int it = 0; it < ITERS; ++it) {
        __syncthreads();   // previous iteration's LDS reads complete
        // commit prefetched tiles to LDS
#pragma unroll
        for (int i = 0; i < 2; ++i) {
            int idx = t + 256 * i;
            *(uint4*)(Klds + (idx >> 3) * 72 + (idx & 7) * 8) = kpre[i];
        }
#pragma unroll
        for (int i = 0; i < 4; ++i) {
            int idx = t + 256 * i;
            bf16x4v bv;
            bv[0] = (__bf16)vpre[i].x; bv[1] = (__bf16)vpre[i].y;
            bv[2] = (__bf16)vpre[i].z; bv[3] = (__bf16)vpre[i].w;
            *(bf16x4v*)(Vlds + (idx >> 4) * 72 + (idx & 15) * 4) = bv;
        }
        __syncthreads();
        // issue next tile's loads (latency hidden behind compute)
        if (it + 1 < ITERS) {
            const int m1 = s * (64 * ITERS) + ((it + 1) << 6);
#pragma unroll
            for (int i = 0; i < 2; ++i) {
                int idx = t + 256 * i;
                kpre[i] = *(const uint4*)(qkT + (size_t)(b * 4096 + m1 + (idx >> 3)) * 64 + (idx & 7) * 8);
            }
#pragma unroll
            for (int i = 0; i < 4; ++i) {
                int idx = t + 256 * i;
                vpre[i] = *(const float4*)(x + (size_t)(b * 64 + (idx >> 4)) * 4096 + m1 + (idx & 15) * 4);
            }
        }

        // S^T = K·Q^T: D row = m_local = quad*4+r, col = q = l16
        bf16x4v pf[4][2];
#pragma unroll
        for (int mt = 0; mt < 4; ++mt) {
            const __bf16* kr = Klds + (mt * 16 + l16) * 72;
            bf16x8v ak0 = *(const bf16x8v*)(kr + quad * 8);
            bf16x8v ak1 = *(const bf16x8v*)(kr + 32 + quad * 8);
#pragma unroll
            for (int qt2 = 0; qt2 < 2; ++qt2) {
                floatx4 sT = {0.f, 0.f, 0.f, 0.f};
                sT = __builtin_amdgcn_mfma_f32_16x16x32_bf16(ak0, fq[qt2][0], sT, 0, 0, 0);
                sT = __builtin_amdgcn_mfma_f32_16x16x32_bf16(ak1, fq[qt2][1], sT, 0, 0, 0);
                float p0 = __expf(sT[0]), p1 = __expf(sT[1]);
                float p2 = __expf(sT[2]), p3 = __expf(sT[3]);
                rs[qt2] += (p0 + p1) + (p2 + p3);
                bf16x4v pv;
                pv[0] = (__bf16)p0; pv[1] = (__bf16)p1; pv[2] = (__bf16)p2; pv[3] = (__bf16)p3;
#if HAVE_MFMA16
                pf[mt][qt2] = pv;
#else
                *(bf16x4v*)(Plds + (w * 32 + qt2 * 16 + l16) * 72 + mt * 16 + quad * 4) = pv;
#endif
            }
        }

#if HAVE_MFMA16
        // O^T += V^T·P^T : A = V^T[c][m] (b64 LDS), B = P^T frags direct from regs
#pragma unroll
        for (int ct = 0; ct < 4; ++ct) {
            const __bf16* vb = Vlds + (ct * 16 + l16) * 72;
#pragma unroll
            for (int mt = 0; mt < 4; ++mt) {
                bf16x4v av = *(const bf16x4v*)(vb + mt * 16 + quad * 4);
#pragma unroll
                for (int qt2 = 0; qt2 < 2; ++qt2)
                    oacc[qt2][ct] = mfma16(av, pf[mt][qt2], oacc[qt2][ct]);
            }
        }
#else
        (void)pf;
        // O += P·V  (A = P[q][m] via LDS roundtrip)
        bf16x8v ap[2][2];
#pragma unroll
        for (int qt2 = 0; qt2 < 2; ++qt2) {
            const __bf16* pr = Plds + (w * 32 + qt2 * 16 + l16) * 72;
            ap[qt2][0] = *(const bf16x8v*)(pr + quad * 8);
            ap[qt2][1] = *(const bf16x8v*)(pr + 32 + quad * 8);
        }
#pragma unroll
        for (int ct = 0; ct < 4; ++ct) {
            const __bf16* vr = Vlds + (ct * 16 + l16) * 72;
            bf16x8v bv0 = *(const bf16x8v*)(vr + quad * 8);
            bf16x8v bv1 = *(const bf16x8v*)(vr + 32 + quad * 8);
#pragma unroll
            for (int qt2 = 0; qt2 < 2; ++qt2) {
                oacc[qt2][ct] = __builtin_amdgcn_mfma_f32_16x16x32_bf16(ap[qt2][0], bv0, oacc[qt2][ct], 0, 0, 0);
                oacc[qt2][ct] = __builtin_amdgcn_mfma_f32_16x16x32_bf16(ap[qt2][1], bv1, oacc[qt2][ct], 0, 0, 0);
            }
        }
#endif
    }

    // rowsum: lane holds partial for q=qt2*16+l16 over its quad's m-rows
#pragma unroll
    for (int qt2 = 0; qt2 < 2; ++qt2) {
        float v = rs[qt2];
        v += __shfl_xor(v, 16, 64);
        v += __shfl_xor(v, 32, 64);
        if (quad == 0)
            Lpart[(size_t)pblk * 128 + w * 32 + qt2 * 16 + l16] = v;
    }

    __syncthreads();   // all LDS tile reads done before aliasing as Olds

#if HAVE_MFMA16
    // O^T D-layout: c = ct*16 + quad*4 + r, q = w*32 + qt2*16 + l16
#pragma unroll
    for (int qt2 = 0; qt2 < 2; ++qt2)
#pragma unroll
        for (int ct = 0; ct < 4; ++ct)
#pragma unroll
            for (int r = 0; r < 4; ++r)
                Olds[(ct * 16 + quad * 4 + r) * 132 + w * 32 + qt2 * 16 + l16] = oacc[qt2][ct][r];
#else
    // O D-layout: q = w*32 + qt2*16 + quad*4 + r, c = ct*16 + l16
#pragma unroll
    for (int qt2 = 0; qt2 < 2; ++qt2)
#pragma unroll
        for (int ct = 0; ct < 4; ++ct)
#pragma unroll
            for (int r = 0; r < 4; ++r)
                Olds[(ct * 16 + l16) * 132 + w * 32 + qt2 * 16 + quad * 4 + r] = oacc[qt2][ct][r];
#endif
    __syncthreads();

    // coalesced bf16 partial stores: Opart[pblk][c][q]
    const int c = t >> 2, seg = t & 3;
#pragma unroll
    for (int i = 0; i < 4; ++i) {
        floatx4 v0 = *(const floatx4*)(Olds + c * 132 + seg * 32 + i * 8);
        floatx4 v1 = *(const floatx4*)(Olds + c * 132 + seg * 32 + i * 8 + 4);
        bf16x8v pk;
        pk[0]=(__bf16)v0[0]; pk[1]=(__bf16)v0[1]; pk[2]=(__bf16)v0[2]; pk[3]=(__bf16)v0[3];
        pk[4]=(__bf16)v1[0]; pk[5]=(__bf16)v1[1]; pk[6]=(__bf16)v1[2]; pk[7]=(__bf16)v1[3];
        *(bf16x8v*)(Opart + (size_t)pblk * 8192 + c * 128 + seg * 32 + i * 8) = pk;
    }
}

// ---------------------------------------------------------------------------
// Kernel 3: combine SPLIT m-chunk partials, normalize, store fp32 output.
// linv staged in LDS once per block (Lpart read 1x, not 16x).
// ---------------------------------------------------------------------------
template<int SPLIT>
__global__ __launch_bounds__(256) void reduce_kernel(const __bf16* __restrict__ Opart,
                                                     const float* __restrict__ Lpart,
                                                     float* __restrict__ out) {
    __shared__ float linv[128];
    const int blk = blockIdx.x;           // bq*4 + cq
    const int bq = blk >> 2, cq = blk & 3;
    const int b = bq >> 5, qt = bq & 31;
    const int t = threadIdx.x;

    if (t < 128) {
        float sl = 0.f;
#pragma unroll
        for (int s = 0; s < SPLIT; ++s)
            sl += Lpart[((size_t)bq * SPLIT + s) * 128 + t];
        linv[t] = 1.0f / sl;
    }
    __syncthreads();

    const int c  = cq * 16 + (t >> 4);     // channel
    const int q8 = (t & 15) * 8;           // q offset (8 per thread)

    float a[8] = {0.f,0.f,0.f,0.f,0.f,0.f,0.f,0.f};
#pragma unroll
    for (int s = 0; s < SPLIT; ++s) {
        bf16x8v v = *(const bf16x8v*)(Opart + ((size_t)bq * SPLIT + s) * 8192 + c * 128 + q8);
#pragma unroll
        for (int k = 0; k < 8; ++k) a[k] += (float)v[k];
    }
    float* op = out + (size_t)(b * 64 + c) * 4096 + qt * 128 + q8;
    float4 o0, o1;
    o0.x = a[0]*linv[q8+0]; o0.y = a[1]*linv[q8+1]; o0.z = a[2]*linv[q8+2]; o0.w = a[3]*linv[q8+3];
    o1.x = a[4]*linv[q8+4]; o1.y = a[5]*linv[q8+5]; o1.z = a[6]*linv[q8+6]; o1.w = a[7]*linv[q8+7];
    *(float4*)op       = o0;
    *(float4*)(op + 4) = o1;
}

// ---------------------------------------------------------------------------
extern "C" void kernel_launch(void* const* d_in, const int* in_sizes, int n_in,
                              void* d_out, int out_size, void* d_ws, size_t ws_size,
                              hipStream_t stream) {
    const float* x    = (const float*)d_in[0];   // [4][64][4096]
    const float* Wm   = (const float*)d_in[1];   // [64][64]
    const float* bias = (const float*)d_in[2];   // [64]
    float* out = (float*)d_out;                  // [4][64][4096]

    char* ws = (char*)d_ws;
    __bf16* qkT = (__bf16*)ws;                   // 2 MB [4][4096][64] bf16

    qk_kernel<<<BATCH * (NSP / 64), 256, 0, stream>>>(x, Wm, bias, qkT);

    const size_t QKT = 2097152;
    const size_t needBig = QKT + (size_t)1024 * 8192 * 2 + (size_t)1024 * 128 * 4;  // ~19.4 MB
    if (ws_size >= needBig) {
        __bf16* Opart = (__bf16*)(ws + QKT);                          // 16 MB [1024][64][128]
        float*  Lpart = (float*)(ws + QKT + (size_t)1024 * 8192 * 2); // 512 KB
        attn_kernel<8, 8><<<BATCH * 32 * 8, 256, 0, stream>>>(x, qkT, Opart, Lpart);
        reduce_kernel<8><<<512, 256, 0, stream>>>(Opart, Lpart, out);
    } else {
        __bf16* Opart = (__bf16*)(ws + QKT);                          // 8 MB [512][64][128]
        float*  Lpart = (float*)(ws + QKT + (size_t)512 * 8192 * 2);  // 256 KB
        attn_kernel<4, 16><<<BATCH * 32 * 4, 256, 0, stream>>>(x, qkT, Opart, Lpart);
        reduce_kernel<4><<<512, 256, 0, stream>>>(Opart, Lpart, out);
    }
}

// Round 9
// 101.763 us; speedup vs baseline: 1.0333x; 1.0333x over previous
//
#include <hip/hip_runtime.h>
#include <hip/hip_bf16.h>

// Problem constants (fixed by reference): B=4, C=64, H=W=64, N=4096
#define BATCH 4
#define NSP   4096

typedef __bf16 bf16x8v __attribute__((ext_vector_type(8)));
typedef __bf16 bf16x4v __attribute__((ext_vector_type(4)));
typedef float  floatx4 __attribute__((ext_vector_type(4)));
typedef short  shortx4 __attribute__((ext_vector_type(4)));

// K=16 bf16 MFMA for direct D->B operand feeding (PV without LDS roundtrip).
// __has_builtin only on the DEVICE pass (host pass probes false — R7).
// Host-pass stub must still be __device__ so calls from __global__ bodies
// semantic-check on the host compile (R8).
#if defined(__HIP_DEVICE_COMPILE__)
#  if __has_builtin(__builtin_amdgcn_mfma_f32_16x16x16bf16_1k)
static __device__ inline floatx4 mfma16(bf16x4v a, bf16x4v b, floatx4 c) {
    return __builtin_amdgcn_mfma_f32_16x16x16bf16_1k(
        __builtin_bit_cast(shortx4, a), __builtin_bit_cast(shortx4, b), c, 0, 0, 0);
}
#  elif __has_builtin(__builtin_amdgcn_mfma_f32_16x16x16_bf16)
static __device__ inline floatx4 mfma16(bf16x4v a, bf16x4v b, floatx4 c) {
    return __builtin_amdgcn_mfma_f32_16x16x16_bf16(a, b, c, 0, 0, 0);
}
#  else
#    error "gfx950 device pass should have a K=16 bf16 mfma builtin"
#  endif
#else
// host-pass stub (never executed, never device-codegenned)
static __device__ inline floatx4 mfma16(bf16x4v, bf16x4v, floatx4 c) { return c; }
#endif

// ---------------------------------------------------------------------------
// Kernel 1: qkT[b][n][o] = bf16( (sum_c W[o][c]*x[b][c][n] + bias[o]) / 64 )
// 1/64 pre-scale on both Q and K makes attn scores come out scaled by 1/4096.
// ---------------------------------------------------------------------------
__global__ __launch_bounds__(256) void qk_kernel(const float* __restrict__ x,
                                                 const float* __restrict__ Wm,
                                                 const float* __restrict__ bias,
                                                 __bf16* __restrict__ qkT) {
    __shared__ __align__(16) __bf16 xT[64 * 72];   // [n][c]; reused as [n][o] out buf

    const int t  = threadIdx.x;
    const int b  = blockIdx.x >> 6;
    const int n0 = (blockIdx.x & 63) << 6;

#pragma unroll
    for (int p = 0; p < 4; ++p) {
        const int c  = p * 16 + (t >> 4);
        const int n4 = (t & 15) * 4;
        const float4 v = *(const float4*)(x + (size_t)(b * 64 + c) * 4096 + n0 + n4);
        xT[(n4 + 0) * 72 + c] = (__bf16)(v.x * 0.015625f);
        xT[(n4 + 1) * 72 + c] = (__bf16)(v.y * 0.015625f);
        xT[(n4 + 2) * 72 + c] = (__bf16)(v.z * 0.015625f);
        xT[(n4 + 3) * 72 + c] = (__bf16)(v.w * 0.015625f);
    }
    __syncthreads();

    const int w = t >> 6, lane = t & 63, quad = lane >> 4, l16 = lane & 15;
    const bf16x8v a0 = *(const bf16x8v*)(xT + (w * 16 + l16) * 72 + quad * 8);
    const bf16x8v a1 = *(const bf16x8v*)(xT + (w * 16 + l16) * 72 + 32 + quad * 8);

    floatx4 acc[4];
#pragma unroll
    for (int ot = 0; ot < 4; ++ot) {
        const float* wr = Wm + (ot * 16 + l16) * 64;
        float4 wa = *(const float4*)(wr + quad * 8);
        float4 wb = *(const float4*)(wr + quad * 8 + 4);
        float4 wc = *(const float4*)(wr + 32 + quad * 8);
        float4 wd = *(const float4*)(wr + 32 + quad * 8 + 4);
        bf16x8v b0, b1;
        b0[0]=(__bf16)wa.x; b0[1]=(__bf16)wa.y; b0[2]=(__bf16)wa.z; b0[3]=(__bf16)wa.w;
        b0[4]=(__bf16)wb.x; b0[5]=(__bf16)wb.y; b0[6]=(__bf16)wb.z; b0[7]=(__bf16)wb.w;
        b1[0]=(__bf16)wc.x; b1[1]=(__bf16)wc.y; b1[2]=(__bf16)wc.z; b1[3]=(__bf16)wc.w;
        b1[4]=(__bf16)wd.x; b1[5]=(__bf16)wd.y; b1[6]=(__bf16)wd.z; b1[7]=(__bf16)wd.w;
        acc[ot] = floatx4{0.f, 0.f, 0.f, 0.f};
        acc[ot] = __builtin_amdgcn_mfma_f32_16x16x32_bf16(a0, b0, acc[ot], 0, 0, 0);
        acc[ot] = __builtin_amdgcn_mfma_f32_16x16x32_bf16(a1, b1, acc[ot], 0, 0, 0);
    }
    __syncthreads();

#pragma unroll
    for (int ot = 0; ot < 4; ++ot) {
        const float bo = bias[ot * 16 + l16] * 0.015625f;
#pragma unroll
        for (int r = 0; r < 4; ++r)
            xT[(w * 16 + quad * 4 + r) * 72 + ot * 16 + l16] = (__bf16)(acc[ot][r] + bo);
    }
    __syncthreads();

    const int n = t >> 2, seg = t & 3;
    __bf16* dst = qkT + (size_t)(b * 4096 + n0 + n) * 64 + seg * 16;
    *(bf16x8v*)dst       = *(const bf16x8v*)(xT + n * 72 + seg * 16);
    *(bf16x8v*)(dst + 8) = *(const bf16x8v*)(xT + n * 72 + seg * 16 + 8);
}

// ---------------------------------------------------------------------------
// Kernel 2: flash-style attention. Block = (b, 128-q tile, m-chunk). 4 waves
// x 32 q. Double-buffered K/V LDS, ONE barrier per iter, prefetch spanning
// the compute phase. S^T = K·Q^T; exp feeds PV directly as K=16 MFMA
// B-operands. V stored in LDS with permuted columns j = quad*16 + mt*4 + r
// so all 4 mt A-frags come from 2 ds_read_b128.
// ---------------------------------------------------------------------------
#define BUFB 18432   // bytes per K+V buffer

template<int SPLIT, int ITERS>
__global__ __launch_bounds__(256, 4) void attn_kernel(const float* __restrict__ x,
                                                      const __bf16* __restrict__ qkT,
                                                      __bf16* __restrict__ Opart,
                                                      float* __restrict__ Lpart) {
    __shared__ __align__(16) char smem[36864];
    float* Olds = (float*)smem;                   // epilogue alias: [64 c][132 q]

    const int t   = threadIdx.x;
    const int blk = blockIdx.x;
    const int xcd = blk & 7;                      // XCD round-robin
    const int b   = xcd >> 1;                     // each b pinned to 2 XCDs
    const int sub = ((blk >> 3) << 1) | (xcd & 1);
    const int qt  = sub / SPLIT;
    const int s   = sub % SPLIT;
    const int n0  = qt << 7;
    const int pblk = (b * 32 + qt) * SPLIT + s;

    const int w = t >> 6, lane = t & 63, quad = lane >> 4, l16 = lane & 15;

    // Q B-frags: B[k=c][n=q], q = w*32 + qt2*16 + l16
    bf16x8v fq[2][2];
#pragma unroll
    for (int qt2 = 0; qt2 < 2; ++qt2) {
        const __bf16* qrow = qkT + (size_t)(b * 4096 + n0 + w * 32 + qt2 * 16 + l16) * 64;
        fq[qt2][0] = *(const bf16x8v*)(qrow + quad * 8);
        fq[qt2][1] = *(const bf16x8v*)(qrow + 32 + quad * 8);
    }

    floatx4 oacc[2][4];
#pragma unroll
    for (int i = 0; i < 2; ++i)
#pragma unroll
        for (int j = 0; j < 4; ++j) oacc[i][j] = floatx4{0.f, 0.f, 0.f, 0.f};
    float rs[2] = {0.f, 0.f};

    // staging address components (constant per thread)
    const int krow = t >> 3, kc8 = (t & 7) * 8;          // K: 2 chunks (t, t+256)
    const int vc   = t >> 4, vk  = t & 15;               // V: 4 chunks
    const int vj   = (vk & 3) * 16 + (vk >> 2) * 4;      // permuted col base
    const __bf16* kgp = qkT + (size_t)b * 4096 * 64 + (size_t)s * (64 * ITERS) * 64;
    const float*  vgp = x + (size_t)b * 64 * 4096 + s * (64 * ITERS);

    // initial prefetch (iter 0)
    uint4  kpre[2];
    float4 vpre[4];
#pragma unroll
    for (int i = 0; i < 2; ++i)
        kpre[i] = *(const uint4*)(kgp + (size_t)(krow + i * 32) * 64 + kc8);
#pragma unroll
    for (int i = 0; i < 4; ++i)
        vpre[i] = *(const float4*)(vgp + (size_t)(vc + i * 16) * 4096 + vk * 4);

    for (int it = 0; it < ITERS; ++it) {
        __bf16* Kb = (__bf16*)(smem + (it & 1) * BUFB);
        __bf16* Vb = (__bf16*)(smem + (it & 1) * BUFB + 9216);

        // ---- commit prefetched tile (regs were loaded a full iter ago).
        // WAR hazard vs compute(it-2) on this buffer is fenced by barrier(it-1).
#pragma unroll
        for (int i = 0; i < 2; ++i)
            *(uint4*)(Kb + (krow + i * 32) * 72 + kc8) = kpre[i];
#pragma unroll
        for (int i = 0; i < 4; ++i) {
            bf16x4v bv;
            bv[0] = (__bf16)vpre[i].x; bv[1] = (__bf16)vpre[i].y;
            bv[2] = (__bf16)vpre[i].z; bv[3] = (__bf16)vpre[i].w;
            *(bf16x4v*)(Vb + (vc + i * 16) * 72 + vj) = bv;
        }
        __syncthreads();   // the ONLY barrier per iter

        // ---- issue next tile's loads (latency spans entire compute phase)
        if (it + 1 < ITERS) {
            const int m1 = (it + 1) << 6;
#pragma unroll
            for (int i = 0; i < 2; ++i)
                kpre[i] = *(const uint4*)(kgp + (size_t)(m1 + krow + i * 32) * 64 + kc8);
#pragma unroll
            for (int i = 0; i < 4; ++i)
                vpre[i] = *(const float4*)(vgp + (size_t)(vc + i * 16) * 4096 + m1 + vk * 4);
        }

        // ---- S^T = K·Q^T: D row = m_local = quad*4+r, col = q = l16
        bf16x4v pf[4][2];
#pragma unroll
        for (int mt = 0; mt < 4; ++mt) {
            const __bf16* kr = Kb + (mt * 16 + l16) * 72;
            bf16x8v ak0 = *(const bf16x8v*)(kr + quad * 8);
            bf16x8v ak1 = *(const bf16x8v*)(kr + 32 + quad * 8);
#pragma unroll
            for (int qt2 = 0; qt2 < 2; ++qt2) {
                floatx4 sT = {0.f, 0.f, 0.f, 0.f};
                sT = __builtin_amdgcn_mfma_f32_16x16x32_bf16(ak0, fq[qt2][0], sT, 0, 0, 0);
                sT = __builtin_amdgcn_mfma_f32_16x16x32_bf16(ak1, fq[qt2][1], sT, 0, 0, 0);
                float p0 = __expf(sT[0]), p1 = __expf(sT[1]);
                float p2 = __expf(sT[2]), p3 = __expf(sT[3]);
                rs[qt2] += (p0 + p1) + (p2 + p3);
                bf16x4v pv;
                pv[0] = (__bf16)p0; pv[1] = (__bf16)p1; pv[2] = (__bf16)p2; pv[3] = (__bf16)p3;
                pf[mt][qt2] = pv;
            }
        }

        // ---- O^T += V^T·P^T : A-frags for all 4 mt from 2 b128 per ct
#pragma unroll
        for (int ct = 0; ct < 4; ++ct) {
            const __bf16* vb = Vb + (ct * 16 + l16) * 72 + quad * 16;
            bf16x8v v01 = *(const bf16x8v*)vb;        // mt0 (elems 0-3), mt1 (4-7)
            bf16x8v v23 = *(const bf16x8v*)(vb + 8);  // mt2, mt3
            bf16x4v av0 = {v01[0], v01[1], v01[2], v01[3]};
            bf16x4v av1 = {v01[4], v01[5], v01[6], v01[7]};
            bf16x4v av2 = {v23[0], v23[1], v23[2], v23[3]};
            bf16x4v av3 = {v23[4], v23[5], v23[6], v23[7]};
#pragma unroll
            for (int qt2 = 0; qt2 < 2; ++qt2) {
                oacc[qt2][ct] = mfma16(av0, pf[0][qt2], oacc[qt2][ct]);
                oacc[qt2][ct] = mfma16(av1, pf[1][qt2], oacc[qt2][ct]);
                oacc[qt2][ct] = mfma16(av2, pf[2][qt2], oacc[qt2][ct]);
                oacc[qt2][ct] = mfma16(av3, pf[3][qt2], oacc[qt2][ct]);
            }
        }
    }

    // rowsum: lane holds partial for q=qt2*16+l16 over its quad's m-rows
#pragma unroll
    for (int qt2 = 0; qt2 < 2; ++qt2) {
        float v = rs[qt2];
        v += __shfl_xor(v, 16, 64);
        v += __shfl_xor(v, 32, 64);
        if (quad == 0)
            Lpart[(size_t)pblk * 128 + w * 32 + qt2 * 16 + l16] = v;
    }

    __syncthreads();   // all LDS tile reads done before aliasing as Olds

    // O^T D-layout: c = ct*16 + quad*4 + r, q = w*32 + qt2*16 + l16
#pragma unroll
    for (int qt2 = 0; qt2 < 2; ++qt2)
#pragma unroll
        for (int ct = 0; ct < 4; ++ct)
#pragma unroll
            for (int r = 0; r < 4; ++r)
                Olds[(ct * 16 + quad * 4 + r) * 132 + w * 32 + qt2 * 16 + l16] = oacc[qt2][ct][r];
    __syncthreads();

    // coalesced bf16 partial stores: Opart[pblk][c][q]
    const int c = t >> 2, seg = t & 3;
#pragma unroll
    for (int i = 0; i < 4; ++i) {
        floatx4 v0 = *(const floatx4*)(Olds + c * 132 + seg * 32 + i * 8);
        floatx4 v1 = *(const floatx4*)(Olds + c * 132 + seg * 32 + i * 8 + 4);
        bf16x8v pk;
        pk[0]=(__bf16)v0[0]; pk[1]=(__bf16)v0[1]; pk[2]=(__bf16)v0[2]; pk[3]=(__bf16)v0[3];
        pk[4]=(__bf16)v1[0]; pk[5]=(__bf16)v1[1]; pk[6]=(__bf16)v1[2]; pk[7]=(__bf16)v1[3];
        *(bf16x8v*)(Opart + (size_t)pblk * 8192 + c * 128 + seg * 32 + i * 8) = pk;
    }
}

// ---------------------------------------------------------------------------
// Kernel 3: combine SPLIT m-chunk partials, normalize, store fp32 output.
// ---------------------------------------------------------------------------
template<int SPLIT>
__global__ __launch_bounds__(256) void reduce_kernel(const __bf16* __restrict__ Opart,
                                                     const float* __restrict__ Lpart,
                                                     float* __restrict__ out) {
    __shared__ float linv[128];
    const int blk = blockIdx.x;           // bq*4 + cq
    const int bq = blk >> 2, cq = blk & 3;
    const int b = bq >> 5, qt = bq & 31;
    const int t = threadIdx.x;

    if (t < 128) {
        float sl = 0.f;
#pragma unroll
        for (int s = 0; s < SPLIT; ++s)
            sl += Lpart[((size_t)bq * SPLIT + s) * 128 + t];
        linv[t] = 1.0f / sl;
    }
    __syncthreads();

    const int c  = cq * 16 + (t >> 4);     // channel
    const int q8 = (t & 15) * 8;           // q offset (8 per thread)

    float a[8] = {0.f,0.f,0.f,0.f,0.f,0.f,0.f,0.f};
#pragma unroll
    for (int s = 0; s < SPLIT; ++s) {
        bf16x8v v = *(const bf16x8v*)(Opart + ((size_t)bq * SPLIT + s) * 8192 + c * 128 + q8);
#pragma unroll
        for (int k = 0; k < 8; ++k) a[k] += (float)v[k];
    }
    float* op = out + (size_t)(b * 64 + c) * 4096 + qt * 128 + q8;
    float4 o0, o1;
    o0.x = a[0]*linv[q8+0]; o0.y = a[1]*linv[q8+1]; o0.z = a[2]*linv[q8+2]; o0.w = a[3]*linv[q8+3];
    o1.x = a[4]*linv[q8+4]; o1.y = a[5]*linv[q8+5]; o1.z = a[6]*linv[q8+6]; o1.w = a[7]*linv[q8+7];
    *(float4*)op       = o0;
    *(float4*)(op + 4) = o1;
}

// ---------------------------------------------------------------------------
extern "C" void kernel_launch(void* const* d_in, const int* in_sizes, int n_in,
                              void* d_out, int out_size, void* d_ws, size_t ws_size,
                              hipStream_t stream) {
    const float* x    = (const float*)d_in[0];   // [4][64][4096]
    const float* Wm   = (const float*)d_in[1];   // [64][64]
    const float* bias = (const float*)d_in[2];   // [64]
    float* out = (float*)d_out;                  // [4][64][4096]

    char* ws = (char*)d_ws;
    __bf16* qkT = (__bf16*)ws;                   // 2 MB [4][4096][64] bf16

    qk_kernel<<<BATCH * (NSP / 64), 256, 0, stream>>>(x, Wm, bias, qkT);

    const size_t QKT = 2097152;
    const size_t needBig = QKT + (size_t)1024 * 8192 * 2 + (size_t)1024 * 128 * 4;  // ~19.4 MB
    if (ws_size >= needBig) {
        __bf16* Opart = (__bf16*)(ws + QKT);                          // 16 MB [1024][64][128]
        float*  Lpart = (float*)(ws + QKT + (size_t)1024 * 8192 * 2); // 512 KB
        attn_kernel<8, 8><<<BATCH * 32 * 8, 256, 0, stream>>>(x, qkT, Opart, Lpart);
        reduce_kernel<8><<<512, 256, 0, stream>>>(Opart, Lpart, out);
    } else {
        __bf16* Opart = (__bf16*)(ws + QKT);                          // 8 MB [512][64][128]
        float*  Lpart = (float*)(ws + QKT + (size_t)512 * 8192 * 2);  // 256 KB
        attn_kernel<4, 16><<<BATCH * 32 * 4, 256, 0, stream>>>(x, qkT, Opart, Lpart);
        reduce_kernel<4><<<512, 256, 0, stream>>>(Opart, Lpart, out);
    }
}